// Round 2
// baseline (314.205 us; speedup 1.0000x reference)
//
#include <hip/hip_runtime.h>

typedef _Float16 half8  __attribute__((ext_vector_type(8)));
typedef _Float16 half4v __attribute__((ext_vector_type(4)));
typedef __fp16   fp16x2 __attribute__((ext_vector_type(2)));   // cvt_pkrtz return type
typedef float    floatx16 __attribute__((ext_vector_type(16)));

#define N_ATOMS 131072
#define NUM_GS  128
#define HIDDEN  512
#define N_MOL   1024

#define BM      128                     // atoms per MLP block (R13: was 64)
#define NB_SIDE (N_ATOMS / BM)          // 1024 blocks per type-side
#define NT32    (HIDDEN / 32)           // 16 n-tiles (32-wide) in fragment layout
#define SH1_LD  (HIDDEN + 8)            // sH1 leading dim (halves)
#define SGH_LD  (NUM_GS + 8)            // sGh leading dim (halves)

// ---- workspace byte offsets ----
#define WS_CNT_OFF     0               // int[2]
#define WS_MOLSUM_OFF  1024            // float[1024]
#define WS_PERM_OFF    9216            // int[131072]
#define WS_W1FA_OFF    533504          // fp16 frags 512*128
#define WS_W1FB_OFF    664576
#define WS_W2FA_OFF    795648          // fp16 frags 512*512
#define WS_W2FB_OFF    1319936
#define WS_ZERO_BYTES  5120            // cnt + mol_sum

// 5-op tanh: 1 - 2/(exp(2x)+1). Saturates correctly at +/-inf.
__device__ __forceinline__ float fast_tanh(float x) {
    float e = exp2f(x * 2.8853900817779268f);   // exp(2x)
    float r = __builtin_amdgcn_rcpf(e + 1.0f);
    return fmaf(-2.0f, r, 1.0f);
}

// ---------------------------------------------------------------------------
// Fused prep kernel (unchanged from R12):
//  blocks [0,512)  : partition atoms by type, 2 global atomics per block.
//  blocks [512,832): pack W1/W2 fp32 [K][512] -> fp16 32x32x16 MFMA fragment
//                    layout [kstep16][ntile32][lane][8] (coalesced 1KB loads).
//  Fragment contract: element (kstep,ntile,lane,j)
//  = W[kstep*16 + (lane>>5)*8 + j][ntile*32 + (lane&31)].
// ---------------------------------------------------------------------------
__global__ __launch_bounds__(256)
void prep_kernel(const int* __restrict__ types,
                 const float* __restrict__ W1A, const float* __restrict__ W1B,
                 const float* __restrict__ W2A, const float* __restrict__ W2B,
                 int* __restrict__ cnt, int* __restrict__ perm,
                 _Float16* __restrict__ W1FA, _Float16* __restrict__ W1FB,
                 _Float16* __restrict__ W2FA, _Float16* __restrict__ W2FB) {
    __shared__ float tile[32][65];
    const int p   = blockIdx.x;
    const int tid = threadIdx.x;

    if (p < 512) {                      // ---- partition, 2 atomics/block ----
        __shared__ int sCA[4];
        __shared__ int sBaseA, sBaseB;
        const int i    = p * 256 + tid;
        const int lane = tid & 63;
        const int w    = tid >> 6;
        const bool isA = (types[i] == 0);
        unsigned long long mask = __ballot(isA);
        unsigned long long lt   = ((unsigned long long)1 << lane) - 1;
        int rA = __popcll(mask & lt);
        if (lane == 0) sCA[w] = __popcll(mask);
        __syncthreads();
        if (tid == 0) {
            int tot = sCA[0] + sCA[1] + sCA[2] + sCA[3];
            sBaseA = atomicAdd(&cnt[0], tot);
            sBaseB = atomicAdd(&cnt[1], 256 - tot);
        }
        __syncthreads();
        int preA = 0;
        #pragma unroll
        for (int k = 0; k < 4; ++k) preA += (k < w) ? sCA[k] : 0;
        int preB = w * 64 - preA;
        int rB   = lane - rA;
        if (isA) perm[sBaseA + preA + rA] = i;
        else     perm[N_ATOMS - 1 - (sBaseB + preB + rB)] = i;
        return;
    }

    // ---- weight pack: block stages K=32 x N=64 region, emits 4 fragments ----
    const float* src; _Float16* dst; int pb;
    if (p < 544)      { src = W1A; dst = W1FA; pb = p - 512; }
    else if (p < 576) { src = W1B; dst = W1FB; pb = p - 544; }
    else if (p < 704) { src = W2A; dst = W2FA; pb = p - 576; }
    else              { src = W2B; dst = W2FB; pb = p - 704; }
    const int bx = pb & 7;
    const int by = pb >> 3;
    const int n0 = bx * 64, k0 = by * 32;
    #pragma unroll
    for (int i = 0; i < 8; ++i) {
        int idx = tid + i * 256;
        int r = idx >> 6, c = idx & 63;
        tile[r][c] = src[(size_t)(k0 + r) * HIDDEN + n0 + c];
    }
    __syncthreads();
    // 4 waves: wave w emits sub-kstep (w>>1), sub-ntile (w&1)
    const int w = tid >> 6, lane = tid & 63;
    const int l5 = lane & 31, h = lane >> 5;
    const int ks_l = w >> 1, nt_l = w & 1;
    half8 v;
    #pragma unroll
    for (int j = 0; j < 8; ++j)
        v[j] = (_Float16)tile[ks_l * 16 + h * 8 + j][nt_l * 32 + l5];
    const int ksg = by * 2 + ks_l;
    const int ntg = bx * 2 + nt_l;
    *(half8*)(dst + (((size_t)ksg * NT32 + ntg) * 64 + lane) * 8) = v;
}

// ---------------------------------------------------------------------------
// Fused per-type MLP, f16 MFMA 32x32x16, BM=128 (Round 13).
// R12 post-mortem: latency-bound on the per-block L2 weight stream (2.6 GB
// aggregate = 47% of L2 peak; MfmaUtil 22%, VALUBusy 35%, HBM 3% -> nothing
// saturated). Fix: BM 64->128 halves weight traffic per atom (1.3 GB), acc
// doubles to [4][2] (8 MFMA / k-step / wave = 64 issue-cycles of cover), and
// launch_bounds(512,2) doubles the register budget so the weight fragments
// are explicitly double-buffered (load ks+1 while computing ks).
// 1 block/CU (133 KB LDS) -> occupancy 25% BY DESIGN: trading TLP for
// ILP + halved L2 pressure.
// Wave w owns hidden [64w, 64w+64) for all 128 atoms.
// ---------------------------------------------------------------------------
__global__ __launch_bounds__(512, 2)
void mlp_kernel(const float* __restrict__ Gs,
                const int*   __restrict__ mol_id,
                const _Float16* __restrict__ W1FA, const _Float16* __restrict__ W2FA,
                const float* __restrict__ b1A, const float* __restrict__ b2A,
                const float* __restrict__ W3A, const float* __restrict__ b3A,
                const float* __restrict__ offA,
                const _Float16* __restrict__ W1FB, const _Float16* __restrict__ W2FB,
                const float* __restrict__ b1B, const float* __restrict__ b2B,
                const float* __restrict__ W3B, const float* __restrict__ b3B,
                const float* __restrict__ offB,
                const int* __restrict__ cnt, const int* __restrict__ perm,
                float* __restrict__ mol_sum) {
    // sBuf holds sGh (128 x 136 halves, 35 KB) early, sH1 (128 x 520, 133 KB) late.
    __shared__ __align__(16) _Float16 sBuf[BM * SH1_LD];
    __shared__ int   sOrig[BM];
    __shared__ float sPart[8][BM];

    _Float16 (*sH1)[SH1_LD] = (_Float16(*)[SH1_LD])sBuf;
    _Float16 (*sGh)[SGH_LD] = (_Float16(*)[SGH_LD])sBuf;

    const int b     = blockIdx.x;
    const int nA    = cnt[0];
    const int sideB = (b >= NB_SIDE) ? 1 : 0;
    const int r0    = (sideB ? b - NB_SIDE : b) * BM;
    const int nSide = sideB ? (N_ATOMS - nA) : nA;
    if (r0 >= nSide) return;

    const _Float16 *W1F, *W2F;
    const float *b1, *b2, *W3;
    float b3off;
    if (!sideB) { W1F = W1FA; W2F = W2FA; b1 = b1A; b2 = b2A; W3 = W3A; b3off = b3A[0] + offA[0]; }
    else        { W1F = W1FB; W2F = W2FB; b1 = b1B; b2 = b2B; W3 = W3B; b3off = b3B[0] + offB[0]; }

    const int tid = threadIdx.x;
    if (tid < BM) {
        int r = r0 + tid;
        int orig = -1;
        if (r < nSide) orig = sideB ? perm[N_ATOMS - 1 - r] : perm[r];
        sOrig[tid] = orig;
    }
    __syncthreads();

    // ---- stage G tile (fp32 -> fp16 via pkrtz): 128 rows x 128 cols = 4096 float4
    #pragma unroll
    for (int i = 0; i < 8; ++i) {
        int idx = tid + 512 * i;
        int row = idx >> 5;             // 32 float4 per row
        int c4  = idx & 31;
        int orig = sOrig[row];
        float4 v = make_float4(0.f, 0.f, 0.f, 0.f);
        if (orig >= 0) v = ((const float4*)(Gs + (size_t)orig * NUM_GS))[c4];
        union { half4v h4; fp16x2 h2[2]; } hu;
        hu.h2[0] = __builtin_amdgcn_cvt_pkrtz(v.x, v.y);
        hu.h2[1] = __builtin_amdgcn_cvt_pkrtz(v.z, v.w);
        *(half4v*)&sGh[row][c4 * 4] = hu.h4;
    }
    __syncthreads();

    const int lane = tid & 63;
    const int wid  = tid >> 6;          // wave owns hidden [64*wid, 64*wid+64)
    const int l5   = lane & 31;
    const int h    = lane >> 5;

    floatx16 acc[4][2];                 // [atom-tile mt][hidden-tile nt]

    // ---- init acc with b1 (hidden = wid*64 + nt*32 + g*8 + h*4 + r) ----
    #pragma unroll
    for (int nt = 0; nt < 2; ++nt)
        #pragma unroll
        for (int g = 0; g < 4; ++g) {
            const float4 bv = *(const float4*)&b1[wid * 64 + nt * 32 + g * 8 + h * 4];
            #pragma unroll
            for (int mt = 0; mt < 4; ++mt) {
                acc[mt][nt][g * 4 + 0] = bv.x;
                acc[mt][nt][g * 4 + 1] = bv.y;
                acc[mt][nt][g * 4 + 2] = bv.z;
                acc[mt][nt][g * 4 + 3] = bv.w;
            }
        }

    // weight-fragment load + 8-MFMA compute helpers (double-buffered)
    #define LOADW(WF, dstv, ks)                                                   \
        {                                                                         \
            dstv[0] = *(const half8*)((WF) + (((size_t)(ks) * NT32 + wid * 2 + 0) * 64 + lane) * 8); \
            dstv[1] = *(const half8*)((WF) + (((size_t)(ks) * NT32 + wid * 2 + 1) * 64 + lane) * 8); \
        }
    #define COMPUTE(SRC, wav, ks)                                                 \
        {                                                                         \
            half8 fb[4];                                                          \
            _Pragma("unroll")                                                     \
            for (int mt = 0; mt < 4; ++mt)                                        \
                fb[mt] = *(const half8*)&SRC[mt * 32 + l5][(ks) * 16 + h * 8];    \
            _Pragma("unroll")                                                     \
            for (int nt = 0; nt < 2; ++nt)                                        \
                _Pragma("unroll")                                                 \
                for (int mt = 0; mt < 4; ++mt)                                    \
                    acc[mt][nt] = __builtin_amdgcn_mfma_f32_32x32x16_f16(         \
                        wav[nt], fb[mt], acc[mt][nt], 0, 0, 0);                   \
        }

    // ====== layer 1: H1^T = W1^T @ G^T (+b1), K=128, 8 k-steps of 16 ======
    {
        half8 waA[2], waB[2];
        LOADW(W1F, waA, 0);
        #pragma unroll
        for (int ks = 0; ks < NUM_GS / 16; ks += 2) {
            LOADW(W1F, waB, ks + 1);
            COMPUTE(sGh, waA, ks);
            if (ks + 2 < NUM_GS / 16) LOADW(W1F, waA, ks + 2);
            COMPUTE(sGh, waB, ks + 1);
        }
    }
    __syncthreads();                    // all waves done reading sGh (aliased with sH1)

    // ---- tanh + PACKED b64 stores: 4 contiguous hidden per reg-quad ----
    #pragma unroll
    for (int mt = 0; mt < 4; ++mt)
        #pragma unroll
        for (int nt = 0; nt < 2; ++nt)
            #pragma unroll
            for (int g = 0; g < 4; ++g) {
                float t0 = fast_tanh(acc[mt][nt][g * 4 + 0]);
                float t1 = fast_tanh(acc[mt][nt][g * 4 + 1]);
                float t2 = fast_tanh(acc[mt][nt][g * 4 + 2]);
                float t3 = fast_tanh(acc[mt][nt][g * 4 + 3]);
                union { half4v h4; fp16x2 h2[2]; } hu;
                hu.h2[0] = __builtin_amdgcn_cvt_pkrtz(t0, t1);
                hu.h2[1] = __builtin_amdgcn_cvt_pkrtz(t2, t3);
                *(half4v*)&sH1[mt * 32 + l5][wid * 64 + nt * 32 + g * 8 + h * 4] = hu.h4;
            }
    __syncthreads();

    // ---- init acc with b2 ----
    #pragma unroll
    for (int nt = 0; nt < 2; ++nt)
        #pragma unroll
        for (int g = 0; g < 4; ++g) {
            const float4 bv = *(const float4*)&b2[wid * 64 + nt * 32 + g * 8 + h * 4];
            #pragma unroll
            for (int mt = 0; mt < 4; ++mt) {
                acc[mt][nt][g * 4 + 0] = bv.x;
                acc[mt][nt][g * 4 + 1] = bv.y;
                acc[mt][nt][g * 4 + 2] = bv.z;
                acc[mt][nt][g * 4 + 3] = bv.w;
            }
        }

    // ====== layer 2: pre2^T = W2^T @ H1^T (+b2), K=512, 32 k-steps ======
    {
        half8 waA[2], waB[2];
        LOADW(W2F, waA, 0);
        #pragma unroll 2
        for (int ks = 0; ks < HIDDEN / 16; ks += 2) {
            LOADW(W2F, waB, ks + 1);
            COMPUTE(sH1, waA, ks);
            if (ks + 2 < HIDDEN / 16) LOADW(W2F, waA, ks + 2);
            COMPUTE(sH1, waB, ks + 1);
        }
    }
    #undef LOADW
    #undef COMPUTE

    // ======== layer 3 fused: e = sum_j tanh(pre2_j)*W3_j + b3 + off ========
    float4 w3v[2][4];
    #pragma unroll
    for (int nt = 0; nt < 2; ++nt)
        #pragma unroll
        for (int g = 0; g < 4; ++g)
            w3v[nt][g] = *(const float4*)&W3[wid * 64 + nt * 32 + g * 8 + h * 4];

    float p[4] = {0.f, 0.f, 0.f, 0.f};
    #pragma unroll
    for (int mt = 0; mt < 4; ++mt)
        #pragma unroll
        for (int nt = 0; nt < 2; ++nt)
            #pragma unroll
            for (int g = 0; g < 4; ++g) {
                p[mt] = fmaf(fast_tanh(acc[mt][nt][g * 4 + 0]), w3v[nt][g].x, p[mt]);
                p[mt] = fmaf(fast_tanh(acc[mt][nt][g * 4 + 1]), w3v[nt][g].y, p[mt]);
                p[mt] = fmaf(fast_tanh(acc[mt][nt][g * 4 + 2]), w3v[nt][g].z, p[mt]);
                p[mt] = fmaf(fast_tanh(acc[mt][nt][g * 4 + 3]), w3v[nt][g].w, p[mt]);
            }
    #pragma unroll
    for (int mt = 0; mt < 4; ++mt) {
        float v = p[mt];
        v += __shfl_xor(v, 32, 64);     // combine the two h-halves (same atom)
        if (lane < 32) sPart[wid][mt * 32 + lane] = v;
    }
    __syncthreads();
    if (tid < BM) {
        int orig = sOrig[tid];
        if (orig >= 0) {
            float e = b3off;
            #pragma unroll
            for (int w = 0; w < 8; ++w) e += sPart[w][tid];
            atomicAdd(&mol_sum[mol_id[orig]], e);
        }
    }
}

// ---------------------------------------------------------------------------
// finalize: per-molecule mean; counts via binary search in sorted mol_id.
// ---------------------------------------------------------------------------
__global__ void finalize_kernel(const float* __restrict__ mol_sum,
                                const int* __restrict__ mol_id,
                                float* __restrict__ out) {
    int m = blockIdx.x * blockDim.x + threadIdx.x;
    if (m >= N_MOL) return;
    int lo0 = 0, hi0 = N_ATOMS;
    while (lo0 < hi0) { int mid = (lo0 + hi0) >> 1; if (mol_id[mid] < m) lo0 = mid + 1; else hi0 = mid; }
    int lo1 = lo0, hi1 = N_ATOMS;
    while (lo1 < hi1) { int mid = (lo1 + hi1) >> 1; if (mol_id[mid] < m + 1) lo1 = mid + 1; else hi1 = mid; }
    float c = (float)(lo1 - lo0);
    out[m] = mol_sum[m] / fmaxf(c, 1.0f);
}

extern "C" void kernel_launch(void* const* d_in, const int* in_sizes, int n_in,
                              void* d_out, int out_size, void* d_ws, size_t ws_size,
                              hipStream_t stream) {
    const float* Gs     = (const float*)d_in[0];
    const int*   types  = (const int*)d_in[1];
    const int*   mol_id = (const int*)d_in[2];
    const float* W1A = (const float*)d_in[3];
    const float* b1A = (const float*)d_in[4];
    const float* W2A = (const float*)d_in[5];
    const float* b2A = (const float*)d_in[6];
    const float* W3A = (const float*)d_in[7];
    const float* b3A = (const float*)d_in[8];
    const float* oA  = (const float*)d_in[9];
    const float* W1B = (const float*)d_in[10];
    const float* b1B = (const float*)d_in[11];
    const float* W2B = (const float*)d_in[12];
    const float* b2B = (const float*)d_in[13];
    const float* W3B = (const float*)d_in[14];
    const float* b3B = (const float*)d_in[15];
    const float* oB  = (const float*)d_in[16];

    char* ws = (char*)d_ws;
    int*      cnt     = (int*)(ws + WS_CNT_OFF);
    float*    mol_sum = (float*)(ws + WS_MOLSUM_OFF);
    int*      perm    = (int*)(ws + WS_PERM_OFF);
    _Float16* W1FA    = (_Float16*)(ws + WS_W1FA_OFF);
    _Float16* W1FB    = (_Float16*)(ws + WS_W1FB_OFF);
    _Float16* W2FA    = (_Float16*)(ws + WS_W2FA_OFF);
    _Float16* W2FB    = (_Float16*)(ws + WS_W2FB_OFF);
    float* out = (float*)d_out;

    hipMemsetAsync(d_ws, 0, WS_ZERO_BYTES, stream);
    prep_kernel<<<832, 256, 0, stream>>>(types, W1A, W1B, W2A, W2B,
                                         cnt, perm,
                                         W1FA, W1FB, W2FA, W2FB);
    mlp_kernel<<<2 * NB_SIDE, 512, 0, stream>>>(
        Gs, mol_id,
        W1FA, W2FA, b1A, b2A, W3A, b3A, oA,
        W1FB, W2FB, b1B, b2B, W3B, b3B, oB,
        cnt, perm, mol_sum);
    finalize_kernel<<<(N_MOL + 255) / 256, 256, 0, stream>>>(mol_sum, mol_id, out);
}

// Round 4
// 277.928 us; speedup vs baseline: 1.1305x; 1.1305x over previous
//
#include <hip/hip_runtime.h>

typedef _Float16 half8  __attribute__((ext_vector_type(8)));
typedef _Float16 half4v __attribute__((ext_vector_type(4)));
typedef __fp16   fp16x2 __attribute__((ext_vector_type(2)));   // cvt_pkrtz return type
typedef float    floatx4 __attribute__((ext_vector_type(4)));

#define N_ATOMS 131072
#define NUM_GS  128
#define HIDDEN  512
#define N_MOL   1024

#define BM      64                      // atoms per MLP block (R14: back to R11's 64)
#define NB_SIDE (N_ATOMS / BM)          // 2048 blocks per type-side
#define NT_TOT  (HIDDEN / 16)           // 32 n-tiles (16-wide) in fragment layout
#define SH1_LD  (HIDDEN + 8)            // sH1 leading dim (halves)
#define SGH_LD  (NUM_GS + 8)            // sGh leading dim (halves)

// ---- workspace byte offsets ----
#define WS_CNT_OFF     0               // int[2]
#define WS_MOLSUM_OFF  1024            // float[1024]
#define WS_PERM_OFF    9216            // int[131072]
#define WS_W1FA_OFF    533504          // fp16 frags 512*128
#define WS_W1FB_OFF    664576
#define WS_W2FA_OFF    795648          // fp16 frags 512*512
#define WS_W2FB_OFF    1319936
#define WS_ZERO_BYTES  5120            // cnt + mol_sum

// 5-op tanh: 1 - 2/(exp(2x)+1). Saturates correctly at +/-inf.
__device__ __forceinline__ float fast_tanh(float x) {
    float e = exp2f(x * 2.8853900817779268f);   // exp(2x)
    float r = __builtin_amdgcn_rcpf(e + 1.0f);
    return fmaf(-2.0f, r, 1.0f);
}

// ---------------------------------------------------------------------------
// Fused prep kernel (R11's 16x16 fragment pack):
//  blocks [0,512)  : partition atoms by type, 2 global atomics per block.
//  blocks [512,832): pack W1/W2 fp32 [K][512] -> fp16 16x16x32 MFMA fragment
//                    layout [ktile32][ntile16][lane][8] (coalesced 1KB loads).
//  Fragment contract: element (kt,nt,lane,j)
//  = W[kt*32 + (lane>>4)*8 + j][nt*16 + (lane&15)].
// ---------------------------------------------------------------------------
__global__ __launch_bounds__(256)
void prep_kernel(const int* __restrict__ types,
                 const float* __restrict__ W1A, const float* __restrict__ W1B,
                 const float* __restrict__ W2A, const float* __restrict__ W2B,
                 int* __restrict__ cnt, int* __restrict__ perm,
                 _Float16* __restrict__ W1FA, _Float16* __restrict__ W1FB,
                 _Float16* __restrict__ W2FA, _Float16* __restrict__ W2FB) {
    __shared__ float tile[32][65];
    const int p   = blockIdx.x;
    const int tid = threadIdx.x;

    if (p < 512) {                      // ---- partition, 2 atomics/block ----
        __shared__ int sCA[4];
        __shared__ int sBaseA, sBaseB;
        const int i    = p * 256 + tid;
        const int lane = tid & 63;
        const int w    = tid >> 6;
        const bool isA = (types[i] == 0);
        unsigned long long mask = __ballot(isA);
        unsigned long long lt   = ((unsigned long long)1 << lane) - 1;
        int rA = __popcll(mask & lt);
        if (lane == 0) sCA[w] = __popcll(mask);
        __syncthreads();
        if (tid == 0) {
            int tot = sCA[0] + sCA[1] + sCA[2] + sCA[3];
            sBaseA = atomicAdd(&cnt[0], tot);
            sBaseB = atomicAdd(&cnt[1], 256 - tot);
        }
        __syncthreads();
        int preA = 0;
        #pragma unroll
        for (int k = 0; k < 4; ++k) preA += (k < w) ? sCA[k] : 0;
        int preB = w * 64 - preA;
        int rB   = lane - rA;
        if (isA) perm[sBaseA + preA + rA] = i;
        else     perm[N_ATOMS - 1 - (sBaseB + preB + rB)] = i;
        return;
    }

    // ---- weight pack: block handles K=32 x N=64 region ----
    const float* src; _Float16* dst; int pb;
    if (p < 544)      { src = W1A; dst = W1FA; pb = p - 512; }
    else if (p < 576) { src = W1B; dst = W1FB; pb = p - 544; }
    else if (p < 704) { src = W2A; dst = W2FA; pb = p - 576; }
    else              { src = W2B; dst = W2FB; pb = p - 704; }
    const int bx = pb & 7;
    const int by = pb >> 3;
    const int n0 = bx * 64, k0 = by * 32;
    #pragma unroll
    for (int i = 0; i < 8; ++i) {
        int idx = tid + i * 256;
        int r = idx >> 6, c = idx & 63;
        tile[r][c] = src[(size_t)(k0 + r) * HIDDEN + n0 + c];
    }
    __syncthreads();
    const int nt_l = tid >> 6, lane = tid & 63;
    const int l15 = lane & 15, q = lane >> 4;
    half8 v;
    #pragma unroll
    for (int j = 0; j < 8; ++j)
        v[j] = (_Float16)tile[q * 8 + j][nt_l * 16 + l15];
    const int ntile = bx * 4 + nt_l;
    *(half8*)(dst + (((size_t)by * NT_TOT + ntile) * 64 + lane) * 8) = v;
}

// ---------------------------------------------------------------------------
// Fused per-type MLP, f16 MFMA 16x16x32, BM=64 (Round 14, resubmitted after
// R3 infra failure).
// R13 post-mortem: occupancy is the binding constraint (2 blk/CU, 4 waves/
// SIMD is the sweet spot); 16x16 gives 16 independent MFMAs per k-step
// (acc reuse distance ~80cy). This round keeps R11's MFMA structure exactly
// and imports R12's VALU cuts via the operand swap at 16x16:
//   H1^T = W1^T @ G^T  -> C: col=atom(lane&15), row=hidden(quad*4+r,
//   r contiguous) -> tanh quad packs to ds_write_b64 (16/wave vs 64 b16),
//   biases folded into MFMA C-init, epilogue reduce = 2 shuffles not 4.
// Wave w owns hidden [64w, 64w+64) (n-tiles [4w,4w+4)) for all 64 atoms.
// ---------------------------------------------------------------------------
__global__ __launch_bounds__(512, 4)
void mlp_kernel(const float* __restrict__ Gs,
                const int*   __restrict__ mol_id,
                const _Float16* __restrict__ W1FA, const _Float16* __restrict__ W2FA,
                const float* __restrict__ b1A, const float* __restrict__ b2A,
                const float* __restrict__ W3A, const float* __restrict__ b3A,
                const float* __restrict__ offA,
                const _Float16* __restrict__ W1FB, const _Float16* __restrict__ W2FB,
                const float* __restrict__ b1B, const float* __restrict__ b2B,
                const float* __restrict__ W3B, const float* __restrict__ b3B,
                const float* __restrict__ offB,
                const int* __restrict__ cnt, const int* __restrict__ perm,
                float* __restrict__ mol_sum) {
    // sBuf holds sGh (64 x 136 halves, 17 KB) early, sH1 (64 x 520, 65 KB) late.
    __shared__ __align__(16) _Float16 sBuf[BM * SH1_LD];
    __shared__ int   sOrig[BM];
    __shared__ float sPart[8][BM];

    _Float16 (*sH1)[SH1_LD] = (_Float16(*)[SH1_LD])sBuf;
    _Float16 (*sGh)[SGH_LD] = (_Float16(*)[SGH_LD])sBuf;

    const int b     = blockIdx.x;
    const int nA    = cnt[0];
    const int sideB = (b >= NB_SIDE) ? 1 : 0;
    const int r0    = (sideB ? b - NB_SIDE : b) * BM;
    const int nSide = sideB ? (N_ATOMS - nA) : nA;
    if (r0 >= nSide) return;

    const _Float16 *W1F, *W2F;
    const float *b1, *b2, *W3;
    float b3off;
    if (!sideB) { W1F = W1FA; W2F = W2FA; b1 = b1A; b2 = b2A; W3 = W3A; b3off = b3A[0] + offA[0]; }
    else        { W1F = W1FB; W2F = W2FB; b1 = b1B; b2 = b2B; W3 = W3B; b3off = b3B[0] + offB[0]; }

    const int tid = threadIdx.x;
    if (tid < BM) {
        int r = r0 + tid;
        int orig = -1;
        if (r < nSide) orig = sideB ? perm[N_ATOMS - 1 - r] : perm[r];
        sOrig[tid] = orig;
    }
    __syncthreads();

    // ---- stage G tile (fp32 -> fp16 via pkrtz): 64 rows x 128 cols = 2048 float4
    #pragma unroll
    for (int i = 0; i < 4; ++i) {
        int idx = tid + 512 * i;
        int row = idx >> 5;             // 32 float4 per row
        int c4  = idx & 31;
        int orig = sOrig[row];
        float4 v = make_float4(0.f, 0.f, 0.f, 0.f);
        if (orig >= 0) v = ((const float4*)(Gs + (size_t)orig * NUM_GS))[c4];
        union { half4v h4; fp16x2 h2[2]; } hu;
        hu.h2[0] = __builtin_amdgcn_cvt_pkrtz(v.x, v.y);
        hu.h2[1] = __builtin_amdgcn_cvt_pkrtz(v.z, v.w);
        *(half4v*)&sGh[row][c4 * 4] = hu.h4;
    }
    __syncthreads();

    const int lane = tid & 63;
    const int wid  = tid >> 6;          // wave owns hidden [64*wid, 64*wid+64)
    const int l15  = lane & 15;
    const int quad = lane >> 4;

    floatx4 acc[4][4];                  // [atom-tile mt][hidden-tile nt]

    // ---- init acc with b1 (hidden = wid*64 + nt*16 + quad*4 + r) ----
    #pragma unroll
    for (int nt = 0; nt < 4; ++nt) {
        const float4 bv = *(const float4*)&b1[wid * 64 + nt * 16 + quad * 4];
        #pragma unroll
        for (int mt = 0; mt < 4; ++mt)
            acc[mt][nt] = (floatx4){bv.x, bv.y, bv.z, bv.w};
    }

    // ====== layer 1: H1^T = W1^T @ G^T (+b1), K=128, 4 k-steps of 32 ======
    #pragma unroll
    for (int ks = 0; ks < NUM_GS / 32; ++ks) {
        half8 gb[4];
        #pragma unroll
        for (int mt = 0; mt < 4; ++mt)
            gb[mt] = *(const half8*)&sGh[mt * 16 + l15][ks * 32 + quad * 8];
        #pragma unroll
        for (int nt = 0; nt < 4; ++nt) {
            int ntile = wid * 4 + nt;
            half8 wa = *(const half8*)(W1F + (((size_t)ks * NT_TOT + ntile) * 64 + lane) * 8);
            #pragma unroll
            for (int mt = 0; mt < 4; ++mt)
                acc[mt][nt] = __builtin_amdgcn_mfma_f32_16x16x32_f16(wa, gb[mt], acc[mt][nt], 0, 0, 0);
        }
    }
    __syncthreads();                    // all waves done reading sGh (aliased with sH1)

    // ---- tanh + PACKED b64 stores: 4 contiguous hidden per reg-quad ----
    #pragma unroll
    for (int mt = 0; mt < 4; ++mt)
        #pragma unroll
        for (int nt = 0; nt < 4; ++nt) {
            float t0 = fast_tanh(acc[mt][nt][0]);
            float t1 = fast_tanh(acc[mt][nt][1]);
            float t2 = fast_tanh(acc[mt][nt][2]);
            float t3 = fast_tanh(acc[mt][nt][3]);
            union { half4v h4; fp16x2 h2[2]; } hu;
            hu.h2[0] = __builtin_amdgcn_cvt_pkrtz(t0, t1);
            hu.h2[1] = __builtin_amdgcn_cvt_pkrtz(t2, t3);
            *(half4v*)&sH1[mt * 16 + l15][wid * 64 + nt * 16 + quad * 4] = hu.h4;
        }
    __syncthreads();

    // ---- init acc with b2 ----
    #pragma unroll
    for (int nt = 0; nt < 4; ++nt) {
        const float4 bv = *(const float4*)&b2[wid * 64 + nt * 16 + quad * 4];
        #pragma unroll
        for (int mt = 0; mt < 4; ++mt)
            acc[mt][nt] = (floatx4){bv.x, bv.y, bv.z, bv.w};
    }

    // ====== layer 2: pre2^T = W2^T @ H1^T (+b2), K=512, 16 k-steps of 32 ======
    #pragma unroll 2
    for (int ks = 0; ks < HIDDEN / 32; ++ks) {
        half8 hb[4];
        #pragma unroll
        for (int mt = 0; mt < 4; ++mt)
            hb[mt] = *(const half8*)&sH1[mt * 16 + l15][ks * 32 + quad * 8];
        #pragma unroll
        for (int nt = 0; nt < 4; ++nt) {
            int ntile = wid * 4 + nt;
            half8 wa = *(const half8*)(W2F + (((size_t)ks * NT_TOT + ntile) * 64 + lane) * 8);
            #pragma unroll
            for (int mt = 0; mt < 4; ++mt)
                acc[mt][nt] = __builtin_amdgcn_mfma_f32_16x16x32_f16(wa, hb[mt], acc[mt][nt], 0, 0, 0);
        }
    }

    // ======== layer 3 fused: e = sum_j tanh(pre2_j)*W3_j + b3 + off ========
    float4 w3v[4];
    #pragma unroll
    for (int nt = 0; nt < 4; ++nt)
        w3v[nt] = *(const float4*)&W3[wid * 64 + nt * 16 + quad * 4];

    float p[4] = {0.f, 0.f, 0.f, 0.f};
    #pragma unroll
    for (int mt = 0; mt < 4; ++mt)
        #pragma unroll
        for (int nt = 0; nt < 4; ++nt) {
            p[mt] = fmaf(fast_tanh(acc[mt][nt][0]), w3v[nt].x, p[mt]);
            p[mt] = fmaf(fast_tanh(acc[mt][nt][1]), w3v[nt].y, p[mt]);
            p[mt] = fmaf(fast_tanh(acc[mt][nt][2]), w3v[nt].z, p[mt]);
            p[mt] = fmaf(fast_tanh(acc[mt][nt][3]), w3v[nt].w, p[mt]);
        }
    #pragma unroll
    for (int mt = 0; mt < 4; ++mt) {
        float v = p[mt];
        v += __shfl_xor(v, 16, 64);     // combine quad groups (same atom col)
        v += __shfl_xor(v, 32, 64);
        if (lane < 16) sPart[wid][mt * 16 + lane] = v;
    }
    __syncthreads();
    if (tid < BM) {
        int orig = sOrig[tid];
        if (orig >= 0) {
            float e = b3off;
            #pragma unroll
            for (int w = 0; w < 8; ++w) e += sPart[w][tid];
            atomicAdd(&mol_sum[mol_id[orig]], e);
        }
    }
}

// ---------------------------------------------------------------------------
// finalize: per-molecule mean; counts via binary search in sorted mol_id.
// ---------------------------------------------------------------------------
__global__ void finalize_kernel(const float* __restrict__ mol_sum,
                                const int* __restrict__ mol_id,
                                float* __restrict__ out) {
    int m = blockIdx.x * blockDim.x + threadIdx.x;
    if (m >= N_MOL) return;
    int lo0 = 0, hi0 = N_ATOMS;
    while (lo0 < hi0) { int mid = (lo0 + hi0) >> 1; if (mol_id[mid] < m) lo0 = mid + 1; else hi0 = mid; }
    int lo1 = lo0, hi1 = N_ATOMS;
    while (lo1 < hi1) { int mid = (lo1 + hi1) >> 1; if (mol_id[mid] < m + 1) lo1 = mid + 1; else hi1 = mid; }
    float c = (float)(lo1 - lo0);
    out[m] = mol_sum[m] / fmaxf(c, 1.0f);
}

extern "C" void kernel_launch(void* const* d_in, const int* in_sizes, int n_in,
                              void* d_out, int out_size, void* d_ws, size_t ws_size,
                              hipStream_t stream) {
    const float* Gs     = (const float*)d_in[0];
    const int*   types  = (const int*)d_in[1];
    const int*   mol_id = (const int*)d_in[2];
    const float* W1A = (const float*)d_in[3];
    const float* b1A = (const float*)d_in[4];
    const float* W2A = (const float*)d_in[5];
    const float* b2A = (const float*)d_in[6];
    const float* W3A = (const float*)d_in[7];
    const float* b3A = (const float*)d_in[8];
    const float* oA  = (const float*)d_in[9];
    const float* W1B = (const float*)d_in[10];
    const float* b1B = (const float*)d_in[11];
    const float* W2B = (const float*)d_in[12];
    const float* b2B = (const float*)d_in[13];
    const float* W3B = (const float*)d_in[14];
    const float* b3B = (const float*)d_in[15];
    const float* oB  = (const float*)d_in[16];

    char* ws = (char*)d_ws;
    int*      cnt     = (int*)(ws + WS_CNT_OFF);
    float*    mol_sum = (float*)(ws + WS_MOLSUM_OFF);
    int*      perm    = (int*)(ws + WS_PERM_OFF);
    _Float16* W1FA    = (_Float16*)(ws + WS_W1FA_OFF);
    _Float16* W1FB    = (_Float16*)(ws + WS_W1FB_OFF);
    _Float16* W2FA    = (_Float16*)(ws + WS_W2FA_OFF);
    _Float16* W2FB    = (_Float16*)(ws + WS_W2FB_OFF);
    float* out = (float*)d_out;

    hipMemsetAsync(d_ws, 0, WS_ZERO_BYTES, stream);
    prep_kernel<<<832, 256, 0, stream>>>(types, W1A, W1B, W2A, W2B,
                                         cnt, perm,
                                         W1FA, W1FB, W2FA, W2FB);
    mlp_kernel<<<2 * NB_SIDE, 512, 0, stream>>>(
        Gs, mol_id,
        W1FA, W2FA, b1A, b2A, W3A, b3A, oA,
        W1FB, W2FB, b1B, b2B, W3B, b3B, oB,
        cnt, perm, mol_sum);
    finalize_kernel<<<(N_MOL + 255) / 256, 256, 0, stream>>>(mol_sum, mol_id, out);
}